// Round 3
// baseline (12155.199 us; speedup 1.0000x reference)
//
#include <hip/hip_runtime.h>

// B=32, T=1024, I=H=512, 2H=1024.
// 4 independent replica groups x 64 WGs x 256 thr (grid=256 = #CUs).
// Each group redundantly computes the full recurrence; outputs partitioned by t&3.
// Sync: per-WG flag array + agent-scope release/acquire fences (no atomic chains,
// no XCD/hwreg assumptions -> liveness guaranteed).

#define NGROUP 4
#define T_STEPS 1024

typedef __bf16 bf8 __attribute__((ext_vector_type(8)));
typedef float  f4  __attribute__((ext_vector_type(4)));

__device__ __forceinline__ f4 mfma16(bf8 a, bf8 b, f4 c) {
    return __builtin_amdgcn_mfma_f32_16x16x32_bf16(a, b, c, 0, 0, 0);
}
__device__ __forceinline__ float sigf(float x)     { return 1.f / (1.f + __expf(-x)); }
__device__ __forceinline__ float tanhfast(float x) { return 1.f - 2.f / (1.f + __expf(2.f * x)); }

// ws layout (bytes):
//   [0,16384)        : flags: group g at g*4096, 64 u32 each
//   [16384,147456)   : final_c f32 [32][2][512]
// d_out (f32 elems):
//   seg0 [0,33554432)        : output copy 1 [B,T,2,H]
//   seg1 [33554432,67108864) : output copy 2
//   seg2 [67108864,...)      : con; scratch during run:
//     ti0 f32 [T*32][512] @ +0
//     xbf bf16 @ +16777216 f32
//     w0hi/w0lo bf16 @ next
//     rings @ +26214400 f32: per group 131072 B {ring0 2x32KB, ring1 2x32KB}

// ---------------- init
__global__ __launch_bounds__(256) void k_init(const float* __restrict__ x,
                                              const float* __restrict__ w_in0,
                                              __bf16* __restrict__ xbf,
                                              __bf16* __restrict__ w0hi,
                                              __bf16* __restrict__ w0lo,
                                              unsigned* __restrict__ wszero,
                                              unsigned* __restrict__ ringz)
{
    size_t id = (size_t)blockIdx.x * 256 + threadIdx.x;
    size_t gs = (size_t)gridDim.x * 256;
    for (size_t i = id; i < 4096; i += gs) wszero[i] = 0u;      // flags
    for (size_t i = id; i < 262144; i += gs) ringz[i] = 0u;     // rings
    for (size_t i = id; i < (size_t)16777216; i += gs) {
        size_t r = i >> 9, c = i & 511;
        size_t b = r & 31, t = r >> 5;
        xbf[i] = (__bf16)x[(((b << 10) + t) << 9) + c];
    }
    for (size_t i = id; i < (size_t)262144; i += gs) {
        size_t n = i >> 9, k = i & 511;
        float v = w_in0[(k << 9) + n];
        __bf16 h = (__bf16)v;
        w0hi[i] = h;
        w0lo[i] = (__bf16)(v - (float)h);
    }
}

// ---------------- pregemm: ti0[t*32+b][h] = x @ W_in_0 + b_in_0
__global__ __launch_bounds__(256) void k_pregemm(const __bf16* __restrict__ xbf,
                                                 const __bf16* __restrict__ w0hi,
                                                 const __bf16* __restrict__ w0lo,
                                                 const float* __restrict__ b_in0,
                                                 float* __restrict__ ti0)
{
    int tid = threadIdx.x, lane = tid & 63, wid = tid >> 6;
    int wg = blockIdx.x;
    int mbase = (wg & 511) * 64 + wid * 16;
    int nbase = (wg >> 9) * 128;
    int col = lane & 15, kgrp = lane >> 4;
    f4 acc[8];
#pragma unroll
    for (int i = 0; i < 8; ++i) acc[i] = (f4){0.f, 0.f, 0.f, 0.f};
    const __bf16* ap = xbf + (size_t)(mbase + col) * 512 + kgrp * 8;
    for (int kk = 0; kk < 16; ++kk) {
        bf8 a = *reinterpret_cast<const bf8*>(ap + kk * 32);
        const __bf16* wb = w0hi + (size_t)(nbase + col) * 512 + kk * 32 + kgrp * 8;
        const __bf16* wl = w0lo + (size_t)(nbase + col) * 512 + kk * 32 + kgrp * 8;
#pragma unroll
        for (int ct = 0; ct < 8; ++ct) {
            bf8 bh = *reinterpret_cast<const bf8*>(wb + (size_t)ct * 16 * 512);
            bf8 bl = *reinterpret_cast<const bf8*>(wl + (size_t)ct * 16 * 512);
            acc[ct] = mfma16(a, bh, acc[ct]);
            acc[ct] = mfma16(a, bl, acc[ct]);
        }
    }
#pragma unroll
    for (int ct = 0; ct < 8; ++ct) {
        int c = nbase + ct * 16 + col;
        float bias = b_in0[c];
#pragma unroll
        for (int r = 0; r < 4; ++r) {
            int row = mbase + kgrp * 4 + r;
            ti0[(size_t)row * 512 + c] = acc[ct][r] + bias;
        }
    }
}

// ---------------- persistent recurrence: 4 groups x 64 WGs, 8 h-cols per WG
__global__ __launch_bounds__(256) void k_recur(
    const float* __restrict__ wh0, const float* __restrict__ bh0g,
    const float* __restrict__ win1, const float* __restrict__ bin1g,
    const float* __restrict__ wh1, const float* __restrict__ bh1g,
    const float* __restrict__ ti0,
    float* __restrict__ out,
    unsigned* __restrict__ ws,
    __bf16* __restrict__ ringbase)
{
    __shared__ __bf16 sW[6][8192];   // wh0 hi/lo, wh1 hi/lo, win1 hi/lo : [16 col][512 k] swizzled
    __shared__ float  sB[3][16];
    __shared__ float  sTi1[32 * 8];

    int tid = threadIdx.x, lane = tid & 63, wid = tid >> 6;
    int g    = blockIdx.x & 3;
    int rank = blockIdx.x >> 2;          // 0..63
    unsigned* flags = ws + (size_t)g * 1024;
    float* fc = (float*)((char*)ws + 16384);
    __bf16* ring0 = ringbase + (size_t)g * 65536;
    __bf16* ring1 = ring0 + 32768;

    int h0 = rank * 8;
    int col = lane & 15, kgrp = lane >> 4;
    int bhalf = wid & 1;
    int rowA = bhalf * 16 + col;

    // weights to LDS (hi+lo bf16 planes, XOR-swizzled)
    for (int i = tid; i < 8192; i += 256) {
        int cl = i & 15, k = i >> 4;
        int sw = (cl * 512 + k) ^ ((cl & 7) << 3);
        int cg = (cl < 8) ? (h0 + cl) : (512 + h0 + (cl - 8));
        float v0 = wh0[(size_t)k * 1024 + cg];
        __bf16 a0 = (__bf16)v0;
        sW[0][sw] = a0; sW[1][sw] = (__bf16)(v0 - (float)a0);
        float v1 = wh1[(size_t)k * 1024 + cg];
        __bf16 a1 = (__bf16)v1;
        sW[2][sw] = a1; sW[3][sw] = (__bf16)(v1 - (float)a1);
        float v2 = (cl < 8) ? win1[(size_t)k * 512 + h0 + cl] : 0.f;
        __bf16 a2 = (__bf16)v2;
        sW[4][sw] = a2; sW[5][sw] = (__bf16)(v2 - (float)a2);
    }
    if (tid < 16) {
        int cg = (tid < 8) ? (h0 + tid) : (512 + h0 + (tid - 8));
        sB[0][tid] = bh0g[cg];
        sB[1][tid] = bh1g[cg];
        sB[2][tid] = (tid < 8) ? bin1g[h0 + tid] : 0.f;
    }
    __syncthreads();

    float c0s[4] = {0.f, 0.f, 0.f, 0.f};
    float c1s[4] = {0.f, 0.f, 0.f, 0.f};

#pragma unroll 1
    for (int ph = 0; ph <= T_STEPS; ++ph) {
        // prefetch ti0 slice for this phase before the spin (hides L3 latency)
        float t0v[4] = {0.f, 0.f, 0.f, 0.f};
        if (wid < 2 && ph < T_STEPS && col < 8) {
#pragma unroll
            for (int r = 0; r < 4; ++r) {
                int b = bhalf * 16 + kgrp * 4 + r;
                t0v[r] = ti0[((size_t)ph * 32 + b) * 512 + h0 + col];
            }
        }

        if (ph > 0) {
            if (wid == 0) {
                unsigned tgt = (unsigned)ph;
                while (true) {
                    unsigned v = __hip_atomic_load(&flags[lane], __ATOMIC_RELAXED,
                                                   __HIP_MEMORY_SCOPE_AGENT);
                    if (__ballot(v >= tgt) == ~0ull) break;
                    __builtin_amdgcn_s_sleep(2);
                }
                __builtin_amdgcn_fence(__ATOMIC_ACQUIRE, "agent");
            }
            __syncthreads();
        }

        f4 accg = {0.f, 0.f, 0.f, 0.f};
        f4 acct = {0.f, 0.f, 0.f, 0.f};
        if (wid < 2) {
            // part A: gates0(ph) and ti1(ph-1), both from m0(ph-1)
            const __bf16* mp = ring0 + ((ph + 1) & 1) * 16384 + (size_t)rowA * 512 + kgrp * 8;
#pragma unroll
            for (int kk = 0; kk < 16; ++kk) {
                bf8 a = *reinterpret_cast<const bf8*>(mp + kk * 32);
                int e = (col * 512 + kk * 32 + kgrp * 8) ^ ((col & 7) << 3);
                accg = mfma16(a, *reinterpret_cast<const bf8*>(&sW[0][e]), accg);
                accg = mfma16(a, *reinterpret_cast<const bf8*>(&sW[1][e]), accg);
                acct = mfma16(a, *reinterpret_cast<const bf8*>(&sW[4][e]), acct);
                acct = mfma16(a, *reinterpret_cast<const bf8*>(&sW[5][e]), acct);
            }
            if (col < 8) {
#pragma unroll
                for (int r = 0; r < 4; ++r) {
                    int b = bhalf * 16 + kgrp * 4 + r;
                    sTi1[b * 8 + col] = acct[r] + sB[2][col];
                }
            }
            if (ph < T_STEPS) {
                float gv[4], go[4];
#pragma unroll
                for (int r = 0; r < 4; ++r) gv[r] = accg[r] + sB[0][col];
#pragma unroll
                for (int r = 0; r < 4; ++r) go[r] = __shfl_xor(gv[r], 8, 64);
                if (col < 8) {
                    int h = h0 + col;
                    int t = ph;
                    bool own = (((unsigned)t & 3u) == (unsigned)g);
#pragma unroll
                    for (int r = 0; r < 4; ++r) {
                        int b = bhalf * 16 + kgrp * 4 + r;
                        float retain = sigf(gv[r]);
                        float merge  = sigf(go[r]);
                        float cv = tanhfast(c0s[r] + retain * t0v[r]);
                        c0s[r] = cv;
                        float mn = (1.f - merge) * t0v[r] + merge * cv;
                        ring0[(ph & 1) * 16384 + b * 512 + h] = (__bf16)mn;
                        if (own) {
                            size_t ob = ((size_t)b * 1024 + t) * 1024 + h;
                            __builtin_nontemporal_store(mn, out + ob);
                            __builtin_nontemporal_store(mn, out + (size_t)33554432 + ob);
                        }
                    }
                }
            }
        } else if (ph >= 1) {
            // part B: gates1(ph-1) from m1(ph-2)
            const __bf16* mp = ring1 + (ph & 1) * 16384 + (size_t)rowA * 512 + kgrp * 8;
#pragma unroll
            for (int kk = 0; kk < 16; ++kk) {
                bf8 a = *reinterpret_cast<const bf8*>(mp + kk * 32);
                int e = (col * 512 + kk * 32 + kgrp * 8) ^ ((col & 7) << 3);
                accg = mfma16(a, *reinterpret_cast<const bf8*>(&sW[2][e]), accg);
                accg = mfma16(a, *reinterpret_cast<const bf8*>(&sW[3][e]), accg);
            }
        }

        __syncthreads();   // sTi1 handoff

        if (wid >= 2 && ph >= 1) {
            int t = ph - 1;
            bool own = (((unsigned)t & 3u) == (unsigned)g);
            float gv[4], go[4];
#pragma unroll
            for (int r = 0; r < 4; ++r) gv[r] = accg[r] + sB[1][col];
#pragma unroll
            for (int r = 0; r < 4; ++r) go[r] = __shfl_xor(gv[r], 8, 64);
            if (col < 8) {
                int h = h0 + col;
#pragma unroll
                for (int r = 0; r < 4; ++r) {
                    int b = bhalf * 16 + kgrp * 4 + r;
                    float retain = sigf(gv[r]);
                    float merge  = sigf(go[r]);
                    float t1v = sTi1[b * 8 + col];
                    float cv = tanhfast(c1s[r] + retain * t1v);
                    c1s[r] = cv;
                    float mn = (1.f - merge) * t1v + merge * cv;
                    ring1[((ph + 1) & 1) * 16384 + b * 512 + h] = (__bf16)mn;
                    if (own) {
                        size_t ob = ((size_t)b * 1024 + t) * 1024 + 512 + h;
                        __builtin_nontemporal_store(mn, out + ob);
                        __builtin_nontemporal_store(mn, out + (size_t)33554432 + ob);
                    }
                }
            }
        }

        asm volatile("s_waitcnt vmcnt(0)" ::: "memory");
        __syncthreads();
        if (ph < T_STEPS && wid == 0) {
            __builtin_amdgcn_fence(__ATOMIC_RELEASE, "agent");
            if (lane == 0)
                __hip_atomic_store(&flags[rank], (unsigned)(ph + 1), __ATOMIC_RELAXED,
                                   __HIP_MEMORY_SCOPE_AGENT);
        }
    }

    // final cell states (group 0 writes; all groups hold identical values)
    if (g == 0 && col < 8) {
        int h = h0 + col;
        int layer = (wid < 2) ? 0 : 1;
#pragma unroll
        for (int r = 0; r < 4; ++r) {
            int b = bhalf * 16 + kgrp * 4 + r;
            fc[((size_t)b * 2 + layer) * 512 + h] = (wid < 2) ? c0s[r] : c1s[r];
        }
    }
}

// ---------------- finalize: broadcast final_c into seg2 (con)
__global__ __launch_bounds__(256) void k_final(const float* __restrict__ fc,
                                               float* __restrict__ seg2)
{
    size_t id = (size_t)blockIdx.x * 256 + threadIdx.x;
    size_t gs = (size_t)gridDim.x * 256;
    for (size_t i = id; i < (size_t)8388608; i += gs) {
        size_t flat = i * 4;
        int h = (int)(flat & 511);
        int l = (int)((flat >> 9) & 1);
        int b = (int)(flat >> 20);
        f4 v = *reinterpret_cast<const f4*>(&fc[((size_t)b * 2 + l) * 512 + h]);
        *reinterpret_cast<f4*>(&seg2[flat]) = v;
    }
}

extern "C" void kernel_launch(void* const* d_in, const int* in_sizes, int n_in,
                              void* d_out, int out_size, void* d_ws, size_t ws_size,
                              hipStream_t stream)
{
    const float* x     = (const float*)d_in[0];
    const float* w_in0 = (const float*)d_in[1];
    const float* b_in0 = (const float*)d_in[2];
    const float* wh0   = (const float*)d_in[3];
    const float* bh0   = (const float*)d_in[4];
    const float* win1  = (const float*)d_in[5];
    const float* bin1  = (const float*)d_in[6];
    const float* wh1   = (const float*)d_in[7];
    const float* bh1   = (const float*)d_in[8];
    float* out = (float*)d_out;

    float*  seg2 = out + (size_t)2 * 33554432;
    float*  ti0  = seg2;
    __bf16* xbf  = (__bf16*)(ti0 + 16777216);
    __bf16* w0hi = xbf + 16777216;
    __bf16* w0lo = w0hi + 262144;
    __bf16* ringbase = (__bf16*)(seg2 + 26214400);

    k_init<<<1024, 256, 0, stream>>>(x, w_in0, xbf, w0hi, w0lo,
                                     (unsigned*)d_ws, (unsigned*)ringbase);
    k_pregemm<<<2048, 256, 0, stream>>>(xbf, w0hi, w0lo, b_in0, ti0);
    k_recur<<<256, 256, 0, stream>>>(wh0, bh0, win1, bin1, wh1, bh1, ti0, out,
                                     (unsigned*)d_ws, ringbase);
    k_final<<<1024, 256, 0, stream>>>((const float*)((char*)d_ws + 16384), seg2);
}

// Round 4
// 10085.650 us; speedup vs baseline: 1.2052x; 1.2052x over previous
//
#include <hip/hip_runtime.h>

// B=32, T=1024, I=H=512, 2H=1024.
// Single group, 64 WGs x 256 thr. m-state exchanged as RELAXED/AGENT atomic
// dwords (packed bf16 pairs) through L3 — no fences, no cache maintenance.
// Flag barrier: per-WG flag array + ballot poll (validated in round 3).

#define T_STEPS 1024

typedef __bf16 bf8 __attribute__((ext_vector_type(8)));
typedef float  f4  __attribute__((ext_vector_type(4)));

__device__ __forceinline__ f4 mfma16(bf8 a, bf8 b, f4 c) {
    return __builtin_amdgcn_mfma_f32_16x16x32_bf16(a, b, c, 0, 0, 0);
}
__device__ __forceinline__ float sigf(float x)     { return 1.f / (1.f + __expf(-x)); }
__device__ __forceinline__ float tanhfast(float x) { return 1.f - 2.f / (1.f + __expf(2.f * x)); }
__device__ __forceinline__ unsigned pack2(float lo, float hi) {
    union { __bf16 h; unsigned short u; } a, b;
    a.h = (__bf16)lo; b.h = (__bf16)hi;
    return ((unsigned)b.u << 16) | (unsigned)a.u;
}

// ws layout (u32 units):
//   [0,64)        : flags, one per WG
//   [64,16448)    : ring0d  2 slots x [32 rows][256 kpairs]
//   [16448,32832) : ring1d
//   byte 131328.. : final_c f32 [32][2][512]
// d_out (f32): seg0 out-copy1, seg1 out-copy2, seg2 con (scratch during run:
//   ti0 f32 [T*32][512], xbf bf16, w0hi/w0lo bf16)

// ---------------- init
__global__ __launch_bounds__(256) void k_init(const float* __restrict__ x,
                                              const float* __restrict__ w_in0,
                                              __bf16* __restrict__ xbf,
                                              __bf16* __restrict__ w0hi,
                                              __bf16* __restrict__ w0lo,
                                              unsigned* __restrict__ ws)
{
    size_t id = (size_t)blockIdx.x * 256 + threadIdx.x;
    size_t gs = (size_t)gridDim.x * 256;
    for (size_t i = id; i < 32832; i += gs) ws[i] = 0u;   // flags + rings
    for (size_t i = id; i < (size_t)16777216; i += gs) {
        size_t r = i >> 9, c = i & 511;
        size_t b = r & 31, t = r >> 5;
        xbf[i] = (__bf16)x[(((b << 10) + t) << 9) + c];
    }
    for (size_t i = id; i < (size_t)262144; i += gs) {
        size_t n = i >> 9, k = i & 511;
        float v = w_in0[(k << 9) + n];
        __bf16 h = (__bf16)v;
        w0hi[i] = h;
        w0lo[i] = (__bf16)(v - (float)h);
    }
}

// ---------------- pregemm: ti0[t*32+b][h] = x @ W_in_0 + b_in_0
__global__ __launch_bounds__(256) void k_pregemm(const __bf16* __restrict__ xbf,
                                                 const __bf16* __restrict__ w0hi,
                                                 const __bf16* __restrict__ w0lo,
                                                 const float* __restrict__ b_in0,
                                                 float* __restrict__ ti0)
{
    int tid = threadIdx.x, lane = tid & 63, wid = tid >> 6;
    int wg = blockIdx.x;
    int mbase = (wg & 511) * 64 + wid * 16;
    int nbase = (wg >> 9) * 128;
    int col = lane & 15, kgrp = lane >> 4;
    f4 acc[8];
#pragma unroll
    for (int i = 0; i < 8; ++i) acc[i] = (f4){0.f, 0.f, 0.f, 0.f};
    const __bf16* ap = xbf + (size_t)(mbase + col) * 512 + kgrp * 8;
    for (int kk = 0; kk < 16; ++kk) {
        bf8 a = *reinterpret_cast<const bf8*>(ap + kk * 32);
        const __bf16* wb = w0hi + (size_t)(nbase + col) * 512 + kk * 32 + kgrp * 8;
        const __bf16* wl = w0lo + (size_t)(nbase + col) * 512 + kk * 32 + kgrp * 8;
#pragma unroll
        for (int ct = 0; ct < 8; ++ct) {
            bf8 bh = *reinterpret_cast<const bf8*>(wb + (size_t)ct * 16 * 512);
            bf8 bl = *reinterpret_cast<const bf8*>(wl + (size_t)ct * 16 * 512);
            acc[ct] = mfma16(a, bh, acc[ct]);
            acc[ct] = mfma16(a, bl, acc[ct]);
        }
    }
#pragma unroll
    for (int ct = 0; ct < 8; ++ct) {
        int c = nbase + ct * 16 + col;
        float bias = b_in0[c];
#pragma unroll
        for (int r = 0; r < 4; ++r) {
            int row = mbase + kgrp * 4 + r;
            ti0[(size_t)row * 512 + c] = acc[ct][r] + bias;
        }
    }
}

// ---------------- persistent recurrence: 64 WGs, 8 h-cols per WG
__global__ __launch_bounds__(256, 1) void k_recur(
    const float* __restrict__ wh0, const float* __restrict__ bh0g,
    const float* __restrict__ win1, const float* __restrict__ bin1g,
    const float* __restrict__ wh1, const float* __restrict__ bh1g,
    const float* __restrict__ ti0,
    float* __restrict__ out,
    unsigned* __restrict__ ws)
{
    __shared__ __bf16 sW[6][8192];   // wh0 hi/lo, wh1 hi/lo, win1 hi/lo
    __shared__ float  sB[3][16];
    __shared__ float  sTi1[32 * 8];

    int tid = threadIdx.x, lane = tid & 63, wid = tid >> 6;
    int rank = blockIdx.x;           // 0..63
    unsigned* flags  = ws;
    unsigned* ring0d = ws + 64;
    unsigned* ring1d = ws + 64 + 16384;
    float* fc = (float*)((char*)ws + 131328);

    int h0 = rank * 8;
    int col = lane & 15, kgrp = lane >> 4;
    int bhalf = wid & 1;
    int rowA = bhalf * 16 + col;

    // weights to LDS (hi+lo bf16 planes, XOR-swizzled)
    for (int i = tid; i < 8192; i += 256) {
        int cl = i & 15, k = i >> 4;
        int sw = (cl * 512 + k) ^ ((cl & 7) << 3);
        int cg = (cl < 8) ? (h0 + cl) : (512 + h0 + (cl - 8));
        float v0 = wh0[(size_t)k * 1024 + cg];
        __bf16 a0 = (__bf16)v0;
        sW[0][sw] = a0; sW[1][sw] = (__bf16)(v0 - (float)a0);
        float v1 = wh1[(size_t)k * 1024 + cg];
        __bf16 a1 = (__bf16)v1;
        sW[2][sw] = a1; sW[3][sw] = (__bf16)(v1 - (float)a1);
        float v2 = (cl < 8) ? win1[(size_t)k * 512 + h0 + cl] : 0.f;
        __bf16 a2 = (__bf16)v2;
        sW[4][sw] = a2; sW[5][sw] = (__bf16)(v2 - (float)a2);
    }
    if (tid < 16) {
        int cg = (tid < 8) ? (h0 + tid) : (512 + h0 + (tid - 8));
        sB[0][tid] = bh0g[cg];
        sB[1][tid] = bh1g[cg];
        sB[2][tid] = (tid < 8) ? bin1g[h0 + tid] : 0.f;
    }
    __syncthreads();

    float c0s[4] = {0.f, 0.f, 0.f, 0.f};
    float c1s[4] = {0.f, 0.f, 0.f, 0.f};

#pragma unroll 1
    for (int ph = 0; ph <= T_STEPS; ++ph) {
        // prefetch ti0 slice before the spin (hides L3 latency under the wait)
        float t0v[4] = {0.f, 0.f, 0.f, 0.f};
        if (wid < 2 && ph < T_STEPS && col < 8) {
#pragma unroll
            for (int r = 0; r < 4; ++r) {
                int b = bhalf * 16 + kgrp * 4 + r;
                t0v[r] = ti0[((size_t)ph * 32 + b) * 512 + h0 + col];
            }
        }

        if (ph > 0) {
            if (wid == 0) {
                unsigned tgt = (unsigned)ph;
                while (true) {
                    unsigned v = __hip_atomic_load(&flags[lane], __ATOMIC_RELAXED,
                                                   __HIP_MEMORY_SCOPE_AGENT);
                    if (__ballot(v >= tgt) == ~0ull) break;
                    __builtin_amdgcn_s_sleep(1);
                }
            }
            __syncthreads();
        }

        float mn0[4];            // layer-0 outputs held for post-flag out-stores
        float mn1[4];
        f4 accg = {0.f, 0.f, 0.f, 0.f};

        if (wid < 2) {
            // ---- part A: gates0(ph) + ti1(ph-1) from m0(ph-1)
            f4 acct = {0.f, 0.f, 0.f, 0.f};
            unsigned au[16][4];
            const unsigned rb = (unsigned)(((ph + 1) & 1) * 8192 + rowA * 256);
#pragma unroll
            for (int kk = 0; kk < 16; ++kk)
#pragma unroll
                for (int j = 0; j < 4; ++j)
                    au[kk][j] = __hip_atomic_load(&ring0d[rb + kk * 16 + kgrp * 4 + j],
                                                  __ATOMIC_RELAXED, __HIP_MEMORY_SCOPE_AGENT);
#pragma unroll
            for (int kk = 0; kk < 16; ++kk) {
                union { unsigned u[4]; bf8 v; } A;
                A.u[0] = au[kk][0]; A.u[1] = au[kk][1];
                A.u[2] = au[kk][2]; A.u[3] = au[kk][3];
                int e = (col * 512 + kk * 32 + kgrp * 8) ^ ((col & 7) << 3);
                accg = mfma16(A.v, *reinterpret_cast<const bf8*>(&sW[0][e]), accg);
                accg = mfma16(A.v, *reinterpret_cast<const bf8*>(&sW[1][e]), accg);
                acct = mfma16(A.v, *reinterpret_cast<const bf8*>(&sW[4][e]), acct);
                acct = mfma16(A.v, *reinterpret_cast<const bf8*>(&sW[5][e]), acct);
            }
            if (col < 8) {
#pragma unroll
                for (int r = 0; r < 4; ++r) {
                    int b = bhalf * 16 + kgrp * 4 + r;
                    sTi1[b * 8 + col] = acct[r] + sB[2][col];
                }
            }
            if (ph < T_STEPS) {
                float gv[4], go[4];
#pragma unroll
                for (int r = 0; r < 4; ++r) gv[r] = accg[r] + sB[0][col];
#pragma unroll
                for (int r = 0; r < 4; ++r) go[r] = __shfl_xor(gv[r], 8, 64);
#pragma unroll
                for (int r = 0; r < 4; ++r) {
                    float retain = sigf(gv[r]);
                    float merge  = sigf(go[r]);
                    float cv = tanhfast(c0s[r] + retain * t0v[r]);   // t0v=0 for col>=8: bounded garbage, unused
                    c0s[r] = cv;
                    mn0[r] = (1.f - merge) * t0v[r] + merge * cv;
                }
                // pack bf16 pairs and store to ring0 (relaxed agent -> L3)
#pragma unroll
                for (int r = 0; r < 4; ++r) {
                    float hi = __shfl_xor(mn0[r], 1, 64);
                    if (col < 8 && !(col & 1)) {
                        int b = bhalf * 16 + kgrp * 4 + r;
                        unsigned pk = pack2(mn0[r], hi);
                        __hip_atomic_store(&ring0d[(ph & 1) * 8192 + b * 256 + rank * 4 + (col >> 1)],
                                           pk, __ATOMIC_RELAXED, __HIP_MEMORY_SCOPE_AGENT);
                    }
                }
            }
        } else if (ph >= 1) {
            // ---- part B: gates1(ph-1) from m1(ph-2)
            unsigned au[16][4];
            const unsigned rb = (unsigned)((ph & 1) * 8192 + rowA * 256);
#pragma unroll
            for (int kk = 0; kk < 16; ++kk)
#pragma unroll
                for (int j = 0; j < 4; ++j)
                    au[kk][j] = __hip_atomic_load(&ring1d[rb + kk * 16 + kgrp * 4 + j],
                                                  __ATOMIC_RELAXED, __HIP_MEMORY_SCOPE_AGENT);
#pragma unroll
            for (int kk = 0; kk < 16; ++kk) {
                union { unsigned u[4]; bf8 v; } A;
                A.u[0] = au[kk][0]; A.u[1] = au[kk][1];
                A.u[2] = au[kk][2]; A.u[3] = au[kk][3];
                int e = (col * 512 + kk * 32 + kgrp * 8) ^ ((col & 7) << 3);
                accg = mfma16(A.v, *reinterpret_cast<const bf8*>(&sW[2][e]), accg);
                accg = mfma16(A.v, *reinterpret_cast<const bf8*>(&sW[3][e]), accg);
            }
        }

        __syncthreads();   // sTi1 handoff

        if (wid >= 2 && ph >= 1) {
            float gv[4], go[4];
#pragma unroll
            for (int r = 0; r < 4; ++r) gv[r] = accg[r] + sB[1][col];
#pragma unroll
            for (int r = 0; r < 4; ++r) go[r] = __shfl_xor(gv[r], 8, 64);
#pragma unroll
            for (int r = 0; r < 4; ++r) {
                int b = bhalf * 16 + kgrp * 4 + r;
                float t1v = (col < 8) ? sTi1[b * 8 + col] : 0.f;
                float retain = sigf(gv[r]);
                float merge  = sigf(go[r]);
                float cv = tanhfast(c1s[r] + retain * t1v);
                c1s[r] = cv;
                mn1[r] = (1.f - merge) * t1v + merge * cv;
            }
#pragma unroll
            for (int r = 0; r < 4; ++r) {
                float hi = __shfl_xor(mn1[r], 1, 64);
                if (col < 8 && !(col & 1)) {
                    int b = bhalf * 16 + kgrp * 4 + r;
                    unsigned pk = pack2(mn1[r], hi);
                    __hip_atomic_store(&ring1d[((ph + 1) & 1) * 8192 + b * 256 + rank * 4 + (col >> 1)],
                                       pk, __ATOMIC_RELAXED, __HIP_MEMORY_SCOPE_AGENT);
                }
            }
        }

        // ring stores globally visible before flag: per-wave drain, then barrier
        asm volatile("s_waitcnt vmcnt(0)" ::: "memory");
        __syncthreads();
        if (ph < T_STEPS && tid == 0)
            __hip_atomic_store(&flags[rank], (unsigned)(ph + 1), __ATOMIC_RELAXED,
                               __HIP_MEMORY_SCOPE_AGENT);

        // output stores AFTER the flag — off the inter-WG critical path
        if (col < 8) {
            int h = h0 + col;
            if (wid < 2 && ph < T_STEPS) {
#pragma unroll
                for (int r = 0; r < 4; ++r) {
                    int b = bhalf * 16 + kgrp * 4 + r;
                    size_t ob = ((size_t)b * 1024 + ph) * 1024 + h;
                    __builtin_nontemporal_store(mn0[r], out + ob);
                    __builtin_nontemporal_store(mn0[r], out + (size_t)33554432 + ob);
                }
            } else if (wid >= 2 && ph >= 1) {
#pragma unroll
                for (int r = 0; r < 4; ++r) {
                    int b = bhalf * 16 + kgrp * 4 + r;
                    size_t ob = ((size_t)b * 1024 + (ph - 1)) * 1024 + 512 + h;
                    __builtin_nontemporal_store(mn1[r], out + ob);
                    __builtin_nontemporal_store(mn1[r], out + (size_t)33554432 + ob);
                }
            }
        }
    }

    // final cell states
    if (col < 8) {
        int h = h0 + col;
        int layer = (wid < 2) ? 0 : 1;
#pragma unroll
        for (int r = 0; r < 4; ++r) {
            int b = bhalf * 16 + kgrp * 4 + r;
            fc[((size_t)b * 2 + layer) * 512 + h] = (wid < 2) ? c0s[r] : c1s[r];
        }
    }
}

// ---------------- finalize: broadcast final_c into seg2 (con)
__global__ __launch_bounds__(256) void k_final(const float* __restrict__ fc,
                                               float* __restrict__ seg2)
{
    size_t id = (size_t)blockIdx.x * 256 + threadIdx.x;
    size_t gs = (size_t)gridDim.x * 256;
    for (size_t i = id; i < (size_t)8388608; i += gs) {
        size_t flat = i * 4;
        int h = (int)(flat & 511);
        int l = (int)((flat >> 9) & 1);
        int b = (int)(flat >> 20);
        f4 v = *reinterpret_cast<const f4*>(&fc[((size_t)b * 2 + l) * 512 + h]);
        *reinterpret_cast<f4*>(&seg2[flat]) = v;
    }
}

extern "C" void kernel_launch(void* const* d_in, const int* in_sizes, int n_in,
                              void* d_out, int out_size, void* d_ws, size_t ws_size,
                              hipStream_t stream)
{
    const float* x     = (const float*)d_in[0];
    const float* w_in0 = (const float*)d_in[1];
    const float* b_in0 = (const float*)d_in[2];
    const float* wh0   = (const float*)d_in[3];
    const float* bh0   = (const float*)d_in[4];
    const float* win1  = (const float*)d_in[5];
    const float* bin1  = (const float*)d_in[6];
    const float* wh1   = (const float*)d_in[7];
    const float* bh1   = (const float*)d_in[8];
    float* out = (float*)d_out;

    float*  seg2 = out + (size_t)2 * 33554432;
    float*  ti0  = seg2;
    __bf16* xbf  = (__bf16*)(ti0 + 16777216);
    __bf16* w0hi = xbf + 16777216;
    __bf16* w0lo = w0hi + 262144;

    k_init<<<1024, 256, 0, stream>>>(x, w_in0, xbf, w0hi, w0lo, (unsigned*)d_ws);
    k_pregemm<<<2048, 256, 0, stream>>>(xbf, w0hi, w0lo, b_in0, ti0);
    k_recur<<<64, 256, 0, stream>>>(wh0, bh0, win1, bin1, wh1, bh1, ti0, out,
                                    (unsigned*)d_ws);
    k_final<<<1024, 256, 0, stream>>>((const float*)((char*)d_ws + 131328), seg2);
}

// Round 5
// 6729.945 us; speedup vs baseline: 1.8061x; 1.4986x over previous
//
#include <hip/hip_runtime.h>

// B=32, T=1024, I=H=512, 2H=1024.
// 64 WGs x 128 thr: WG=(rank 0..31: 16 h-cols, mhalf 0..1: 16 batch rows).
// wave0 = layer0 (part A), wave1 = layer1 (part B, 1-phase slack).
// Sync: split per-mhalf flag arrays, relaxed agent atomics (validated r4),
// consumer-only polling with backoff. Rings as packed-bf16 atomic dwords.

#define T_STEPS 1024

typedef __bf16 bf8 __attribute__((ext_vector_type(8)));
typedef float  f4  __attribute__((ext_vector_type(4)));

__device__ __forceinline__ f4 mfma16(bf8 a, bf8 b, f4 c) {
    return __builtin_amdgcn_mfma_f32_16x16x32_bf16(a, b, c, 0, 0, 0);
}
__device__ __forceinline__ float sigf(float x)     { return 1.f / (1.f + __expf(-x)); }
__device__ __forceinline__ float tanhfast(float x) { return 1.f - 2.f / (1.f + __expf(2.f * x)); }
__device__ __forceinline__ unsigned pack2(float lo, float hi) {
    union { __bf16 h; unsigned short u; } a, b;
    a.h = (__bf16)lo; b.h = (__bf16)hi;
    return ((unsigned)b.u << 16) | (unsigned)a.u;
}

// ws layout (u32 units):
//   [0,32)/[64,96)     : flagsA mhalf 0/1
//   [128,160)/[192,224): flagsB mhalf 0/1
//   [256,16640)        : ring0  2 slots x [32 rows][256 kpairs]
//   [16640,33024)      : ring1
//   [33024,65792)      : final_c f32 [32][2][512]
// d_out (f32): seg0 out1, seg1 out2, seg2 con (scratch: ti0, xbf, w0hi/w0lo)

__global__ __launch_bounds__(256) void k_init(const float* __restrict__ x,
                                              const float* __restrict__ w_in0,
                                              __bf16* __restrict__ xbf,
                                              __bf16* __restrict__ w0hi,
                                              __bf16* __restrict__ w0lo,
                                              unsigned* __restrict__ ws)
{
    size_t id = (size_t)blockIdx.x * 256 + threadIdx.x;
    size_t gs = (size_t)gridDim.x * 256;
    for (size_t i = id; i < 33024; i += gs) ws[i] = 0u;   // flags + rings
    for (size_t i = id; i < (size_t)16777216; i += gs) {
        size_t r = i >> 9, c = i & 511;
        size_t b = r & 31, t = r >> 5;
        xbf[i] = (__bf16)x[(((b << 10) + t) << 9) + c];
    }
    for (size_t i = id; i < (size_t)262144; i += gs) {
        size_t n = i >> 9, k = i & 511;
        float v = w_in0[(k << 9) + n];
        __bf16 h = (__bf16)v;
        w0hi[i] = h;
        w0lo[i] = (__bf16)(v - (float)h);
    }
}

__global__ __launch_bounds__(256) void k_pregemm(const __bf16* __restrict__ xbf,
                                                 const __bf16* __restrict__ w0hi,
                                                 const __bf16* __restrict__ w0lo,
                                                 const float* __restrict__ b_in0,
                                                 float* __restrict__ ti0)
{
    int tid = threadIdx.x, lane = tid & 63, wid = tid >> 6;
    int wg = blockIdx.x;
    int mbase = (wg & 511) * 64 + wid * 16;
    int nbase = (wg >> 9) * 128;
    int col = lane & 15, kgrp = lane >> 4;
    f4 acc[8];
#pragma unroll
    for (int i = 0; i < 8; ++i) acc[i] = (f4){0.f, 0.f, 0.f, 0.f};
    const __bf16* ap = xbf + (size_t)(mbase + col) * 512 + kgrp * 8;
    for (int kk = 0; kk < 16; ++kk) {
        bf8 a = *reinterpret_cast<const bf8*>(ap + kk * 32);
        const __bf16* wb = w0hi + (size_t)(nbase + col) * 512 + kk * 32 + kgrp * 8;
        const __bf16* wl = w0lo + (size_t)(nbase + col) * 512 + kk * 32 + kgrp * 8;
#pragma unroll
        for (int ct = 0; ct < 8; ++ct) {
            bf8 bh = *reinterpret_cast<const bf8*>(wb + (size_t)ct * 16 * 512);
            bf8 bl = *reinterpret_cast<const bf8*>(wl + (size_t)ct * 16 * 512);
            acc[ct] = mfma16(a, bh, acc[ct]);
            acc[ct] = mfma16(a, bl, acc[ct]);
        }
    }
#pragma unroll
    for (int ct = 0; ct < 8; ++ct) {
        int c = nbase + ct * 16 + col;
        float bias = b_in0[c];
#pragma unroll
        for (int r = 0; r < 4; ++r) {
            int row = mbase + kgrp * 4 + r;
            ti0[(size_t)row * 512 + c] = acc[ct][r] + bias;
        }
    }
}

// ---------------- persistent recurrence
__global__ __launch_bounds__(128, 1) void k_recur(
    const float* __restrict__ wh0, const float* __restrict__ bh0g,
    const float* __restrict__ win1, const float* __restrict__ bin1g,
    const float* __restrict__ wh1, const float* __restrict__ bh1g,
    const float* __restrict__ ti0,
    float* __restrict__ out,
    unsigned* __restrict__ ws)
{
    // planes: 0:w0r_hi 1:w0r_lo 2:w0m_hi 3:w0m_lo 4:w1r_hi 5:w1r_lo 6:w1m_hi 7:w1m_lo 8:wt_hi
    __shared__ __bf16 sW[9][8192];
    __shared__ float  sTi1[2][256];
    __shared__ float  sB[5][16];

    int tid = threadIdx.x, lane = tid & 63, wid = tid >> 6;   // wid 0=A,1=B
    int wg = blockIdx.x;
    int rank  = wg & 31;
    int mhalf = wg >> 5;

    unsigned* flagsA = ws + mhalf * 64;
    unsigned* flagsB = ws + 128 + mhalf * 64;
    unsigned* ring0d = ws + 256;
    unsigned* ring1d = ws + 256 + 16384;
    float* fc = (float*)(ws + 33024);

    int h0 = rank * 16;
    int col = lane & 15, kgrp = lane >> 4;
    int rbrow = mhalf * 16;            // this WG's batch-row base

    // ---- weights to LDS (XOR-swizzled)
    for (int i = tid; i < 8192; i += 128) {
        int cl = i & 15, k = i >> 4;
        int sw = (cl * 512 + k) ^ ((cl & 7) << 3);
        float v0r = wh0[(size_t)k * 1024 + h0 + cl];
        float v0m = wh0[(size_t)k * 1024 + 512 + h0 + cl];
        float v1r = wh1[(size_t)k * 1024 + h0 + cl];
        float v1m = wh1[(size_t)k * 1024 + 512 + h0 + cl];
        float vt  = win1[(size_t)k * 512 + h0 + cl];
        __bf16 a;
        a = (__bf16)v0r; sW[0][sw] = a; sW[1][sw] = (__bf16)(v0r - (float)a);
        a = (__bf16)v0m; sW[2][sw] = a; sW[3][sw] = (__bf16)(v0m - (float)a);
        a = (__bf16)v1r; sW[4][sw] = a; sW[5][sw] = (__bf16)(v1r - (float)a);
        a = (__bf16)v1m; sW[6][sw] = a; sW[7][sw] = (__bf16)(v1m - (float)a);
        sW[8][sw] = (__bf16)vt;
    }
    if (tid < 16) {
        sB[0][tid] = bh0g[h0 + tid];
        sB[1][tid] = bh0g[512 + h0 + tid];
        sB[2][tid] = bh1g[h0 + tid];
        sB[3][tid] = bh1g[512 + h0 + tid];
        sB[4][tid] = bin1g[h0 + tid];
    }
    __syncthreads();

    float cs[4] = {0.f, 0.f, 0.f, 0.f};   // c0 (wave A) / c1 (wave B)

#pragma unroll 1
    for (int ph = 0; ph <= T_STEPS; ++ph) {
        f4 accR = {0.f, 0.f, 0.f, 0.f};
        f4 accM = {0.f, 0.f, 0.f, 0.f};
        float t0v[4];

        if (wid == 0) {
            // ---- part A pre-sync: gates0(ph) + ti1(ph-1) from m0(ph-1)
            if (ph < T_STEPS) {
#pragma unroll
                for (int r = 0; r < 4; ++r)
                    t0v[r] = ti0[((size_t)ph * 32 + rbrow + kgrp * 4 + r) * 512 + h0 + col];
            }
            if (ph > 0) {
                const unsigned tgt = (unsigned)ph;
                const unsigned* fp = flagsA + (lane & 31);
                while (true) {
                    unsigned v = __hip_atomic_load(fp, __ATOMIC_RELAXED,
                                                   __HIP_MEMORY_SCOPE_AGENT);
                    if (__ballot(v >= tgt) == ~0ull) break;
                    __builtin_amdgcn_s_sleep(1);
                }
                __builtin_amdgcn_sched_barrier(0);
            }
            unsigned au[16][4];
            const unsigned rb = (unsigned)(((ph + 1) & 1) * 8192 + (rbrow + col) * 256);
#pragma unroll
            for (int kk = 0; kk < 16; ++kk)
#pragma unroll
                for (int j = 0; j < 4; ++j)
                    au[kk][j] = __hip_atomic_load(&ring0d[rb + kk * 16 + kgrp * 4 + j],
                                                  __ATOMIC_RELAXED, __HIP_MEMORY_SCOPE_AGENT);
            f4 accT = {0.f, 0.f, 0.f, 0.f};
#pragma unroll
            for (int kk = 0; kk < 16; ++kk) {
                union { unsigned u[4]; bf8 v; } A;
                A.u[0] = au[kk][0]; A.u[1] = au[kk][1];
                A.u[2] = au[kk][2]; A.u[3] = au[kk][3];
                int e = (col * 512 + kk * 32 + kgrp * 8) ^ ((col & 7) << 3);
                accR = mfma16(A.v, *reinterpret_cast<const bf8*>(&sW[0][e]), accR);
                accR = mfma16(A.v, *reinterpret_cast<const bf8*>(&sW[1][e]), accR);
                accM = mfma16(A.v, *reinterpret_cast<const bf8*>(&sW[2][e]), accM);
                accM = mfma16(A.v, *reinterpret_cast<const bf8*>(&sW[3][e]), accM);
                accT = mfma16(A.v, *reinterpret_cast<const bf8*>(&sW[8][e]), accT);
            }
#pragma unroll
            for (int r = 0; r < 4; ++r)
                sTi1[ph & 1][(kgrp * 4 + r) * 16 + col] = accT[r] + sB[4][col];
        } else if (ph >= 1) {
            // ---- part B pre-sync: gates1(ph-1) from m1(ph-2)
            if (ph >= 2) {
                const unsigned tgt = (unsigned)(ph - 1);
                const unsigned* fp = flagsB + (lane & 31);
                while (true) {
                    unsigned v = __hip_atomic_load(fp, __ATOMIC_RELAXED,
                                                   __HIP_MEMORY_SCOPE_AGENT);
                    if (__ballot(v >= tgt) == ~0ull) break;
                    __builtin_amdgcn_s_sleep(1);
                }
                __builtin_amdgcn_sched_barrier(0);
            }
            unsigned au[16][4];
            const unsigned rb = (unsigned)((ph & 1) * 8192 + (rbrow + col) * 256);
#pragma unroll
            for (int kk = 0; kk < 16; ++kk)
#pragma unroll
                for (int j = 0; j < 4; ++j)
                    au[kk][j] = __hip_atomic_load(&ring1d[rb + kk * 16 + kgrp * 4 + j],
                                                  __ATOMIC_RELAXED, __HIP_MEMORY_SCOPE_AGENT);
#pragma unroll
            for (int kk = 0; kk < 16; ++kk) {
                union { unsigned u[4]; bf8 v; } A;
                A.u[0] = au[kk][0]; A.u[1] = au[kk][1];
                A.u[2] = au[kk][2]; A.u[3] = au[kk][3];
                int e = (col * 512 + kk * 32 + kgrp * 8) ^ ((col & 7) << 3);
                accR = mfma16(A.v, *reinterpret_cast<const bf8*>(&sW[4][e]), accR);
                accR = mfma16(A.v, *reinterpret_cast<const bf8*>(&sW[5][e]), accR);
                accM = mfma16(A.v, *reinterpret_cast<const bf8*>(&sW[6][e]), accM);
                accM = mfma16(A.v, *reinterpret_cast<const bf8*>(&sW[7][e]), accM);
            }
        }

        __syncthreads();   // sTi1 handoff (B reads slot ph&1 written by A this phase)

        if (wid == 0) {
            if (ph < T_STEPS) {
                float mn[4];
#pragma unroll
                for (int r = 0; r < 4; ++r) {
                    float retain = sigf(accR[r] + sB[0][col]);
                    float merge  = sigf(accM[r] + sB[1][col]);
                    float cv = tanhfast(cs[r] + retain * t0v[r]);
                    cs[r] = cv;
                    mn[r] = (1.f - merge) * t0v[r] + merge * cv;
                }
                // ring0 stores (packed pairs), drain, flagA
#pragma unroll
                for (int r = 0; r < 4; ++r) {
                    float hi = __shfl_xor(mn[r], 1, 64);
                    if (!(col & 1)) {
                        int grow = rbrow + kgrp * 4 + r;
                        __hip_atomic_store(&ring0d[(ph & 1) * 8192 + grow * 256 + rank * 8 + (col >> 1)],
                                           pack2(mn[r], hi), __ATOMIC_RELAXED,
                                           __HIP_MEMORY_SCOPE_AGENT);
                    }
                }
                asm volatile("s_waitcnt vmcnt(0)" ::: "memory");
                if (lane == 0)
                    __hip_atomic_store(&flagsA[rank], (unsigned)(ph + 1), __ATOMIC_RELAXED,
                                       __HIP_MEMORY_SCOPE_AGENT);
                // out stores after flag (off critical path)
#pragma unroll
                for (int r = 0; r < 4; ++r) {
                    int b = rbrow + kgrp * 4 + r;
                    size_t ob = ((size_t)b * 1024 + ph) * 1024 + h0 + col;
                    __builtin_nontemporal_store(mn[r], out + ob);
                    __builtin_nontemporal_store(mn[r], out + (size_t)33554432 + ob);
                }
            }
        } else if (ph >= 1) {
            float mn[4];
#pragma unroll
            for (int r = 0; r < 4; ++r) {
                float t1v = sTi1[ph & 1][(kgrp * 4 + r) * 16 + col];
                float retain = sigf(accR[r] + sB[2][col]);
                float merge  = sigf(accM[r] + sB[3][col]);
                float cv = tanhfast(cs[r] + retain * t1v);
                cs[r] = cv;
                mn[r] = (1.f - merge) * t1v + merge * cv;
            }
#pragma unroll
            for (int r = 0; r < 4; ++r) {
                float hi = __shfl_xor(mn[r], 1, 64);
                if (!(col & 1)) {
                    int grow = rbrow + kgrp * 4 + r;
                    __hip_atomic_store(&ring1d[((ph + 1) & 1) * 8192 + grow * 256 + rank * 8 + (col >> 1)],
                                       pack2(mn[r], hi), __ATOMIC_RELAXED,
                                       __HIP_MEMORY_SCOPE_AGENT);
                }
            }
            asm volatile("s_waitcnt vmcnt(0)" ::: "memory");
            if (lane == 0)
                __hip_atomic_store(&flagsB[rank], (unsigned)ph, __ATOMIC_RELAXED,
                                   __HIP_MEMORY_SCOPE_AGENT);
#pragma unroll
            for (int r = 0; r < 4; ++r) {
                int b = rbrow + kgrp * 4 + r;
                size_t ob = ((size_t)b * 1024 + (ph - 1)) * 1024 + 512 + h0 + col;
                __builtin_nontemporal_store(mn[r], out + ob);
                __builtin_nontemporal_store(mn[r], out + (size_t)33554432 + ob);
            }
        }
    }

    // final cell states: layer = wid; rows rbrow..rbrow+15, cols h0..h0+15
    {
        int layer = wid;
#pragma unroll
        for (int r = 0; r < 4; ++r) {
            int b = rbrow + kgrp * 4 + r;
            fc[((size_t)b * 2 + layer) * 512 + h0 + col] = cs[r];
        }
    }
}

__global__ __launch_bounds__(256) void k_final(const float* __restrict__ fc,
                                               float* __restrict__ seg2)
{
    size_t id = (size_t)blockIdx.x * 256 + threadIdx.x;
    size_t gs = (size_t)gridDim.x * 256;
    for (size_t i = id; i < (size_t)8388608; i += gs) {
        size_t flat = i * 4;
        int h = (int)(flat & 511);
        int l = (int)((flat >> 9) & 1);
        int b = (int)(flat >> 20);
        f4 v = *reinterpret_cast<const f4*>(&fc[((size_t)b * 2 + l) * 512 + h]);
        *reinterpret_cast<f4*>(&seg2[flat]) = v;
    }
}

extern "C" void kernel_launch(void* const* d_in, const int* in_sizes, int n_in,
                              void* d_out, int out_size, void* d_ws, size_t ws_size,
                              hipStream_t stream)
{
    const float* x     = (const float*)d_in[0];
    const float* w_in0 = (const float*)d_in[1];
    const float* b_in0 = (const float*)d_in[2];
    const float* wh0   = (const float*)d_in[3];
    const float* bh0   = (const float*)d_in[4];
    const float* win1  = (const float*)d_in[5];
    const float* bin1  = (const float*)d_in[6];
    const float* wh1   = (const float*)d_in[7];
    const float* bh1   = (const float*)d_in[8];
    float* out = (float*)d_out;

    float*  seg2 = out + (size_t)2 * 33554432;
    float*  ti0  = seg2;
    __bf16* xbf  = (__bf16*)(ti0 + 16777216);
    __bf16* w0hi = xbf + 16777216;
    __bf16* w0lo = w0hi + 262144;

    k_init<<<1024, 256, 0, stream>>>(x, w_in0, xbf, w0hi, w0lo, (unsigned*)d_ws);
    k_pregemm<<<2048, 256, 0, stream>>>(xbf, w0hi, w0lo, b_in0, ti0);
    k_recur<<<64, 128, 0, stream>>>(wh0, bh0, win1, bin1, wh1, bh1, ti0, out,
                                    (unsigned*)d_ws);
    k_final<<<1024, 256, 0, stream>>>((const float*)((unsigned*)d_ws + 33024), seg2);
}

// Round 6
// 5325.406 us; speedup vs baseline: 2.2825x; 1.2637x over previous
//
#include <hip/hip_runtime.h>

// B=32, T=1024, I=H=512, 2H=1024.
// 64 WGs x 192 thr (3 waves): wave0=A(layer0, critical cycle), wave1=B(layer1,
// 1-phase slack), wave2=C(layer0 out-stores). No intra-loop __syncthreads:
// LDS slot handoffs with workgroup-scope atomics. Inter-WG: relaxed agent
// atomics (sc1, validated r3-r5); ring pulls as global_load_dwordx4 sc1.

#define T_STEPS 1024

typedef __bf16 bf8 __attribute__((ext_vector_type(8)));
typedef float  f4  __attribute__((ext_vector_type(4)));
typedef unsigned u32x4 __attribute__((ext_vector_type(4)));

__device__ __forceinline__ f4 mfma16(bf8 a, bf8 b, f4 c) {
    return __builtin_amdgcn_mfma_f32_16x16x32_bf16(a, b, c, 0, 0, 0);
}
__device__ __forceinline__ float sigf(float x)     { return 1.f / (1.f + __expf(-x)); }
__device__ __forceinline__ float tanhfast(float x) { return 1.f - 2.f / (1.f + __expf(2.f * x)); }
__device__ __forceinline__ unsigned pack2(float lo, float hi) {
    union { __bf16 h; unsigned short u; } a, b;
    a.h = (__bf16)lo; b.h = (__bf16)hi;
    return ((unsigned)b.u << 16) | (unsigned)a.u;
}
__device__ __forceinline__ void wait_lds_ge(int* p, int tgt) {
    while (__hip_atomic_load(p, __ATOMIC_ACQUIRE, __HIP_MEMORY_SCOPE_WORKGROUP) < tgt)
        __builtin_amdgcn_s_sleep(1);
}
__device__ __forceinline__ void set_lds(int* p, int v) {
    __hip_atomic_store(p, v, __ATOMIC_RELEASE, __HIP_MEMORY_SCOPE_WORKGROUP);
}

// ws layout (u32 units):
//   [0,32)/[64,96)     : flagsA mhalf 0/1
//   [128,160)/[192,224): flagsB mhalf 0/1
//   [256,16640)        : ring0  2 slots x [32 rows][256 kpairs]
//   [16640,33024)      : ring1
//   [33024,65792)      : final_c f32 [32][2][512]
// d_out (f32): seg0 out1, seg1 out2, seg2 con (scratch: ti0, xbf, w0hi/w0lo)

__global__ __launch_bounds__(256) void k_init(const float* __restrict__ x,
                                              const float* __restrict__ w_in0,
                                              __bf16* __restrict__ xbf,
                                              __bf16* __restrict__ w0hi,
                                              __bf16* __restrict__ w0lo,
                                              unsigned* __restrict__ ws)
{
    size_t id = (size_t)blockIdx.x * 256 + threadIdx.x;
    size_t gs = (size_t)gridDim.x * 256;
    for (size_t i = id; i < 33024; i += gs) ws[i] = 0u;   // flags + rings
    for (size_t i = id; i < (size_t)16777216; i += gs) {
        size_t r = i >> 9, c = i & 511;
        size_t b = r & 31, t = r >> 5;
        xbf[i] = (__bf16)x[(((b << 10) + t) << 9) + c];
    }
    for (size_t i = id; i < (size_t)262144; i += gs) {
        size_t n = i >> 9, k = i & 511;
        float v = w_in0[(k << 9) + n];
        __bf16 h = (__bf16)v;
        w0hi[i] = h;
        w0lo[i] = (__bf16)(v - (float)h);
    }
}

__global__ __launch_bounds__(256) void k_pregemm(const __bf16* __restrict__ xbf,
                                                 const __bf16* __restrict__ w0hi,
                                                 const __bf16* __restrict__ w0lo,
                                                 const float* __restrict__ b_in0,
                                                 float* __restrict__ ti0)
{
    int tid = threadIdx.x, lane = tid & 63, wid = tid >> 6;
    int wg = blockIdx.x;
    int mbase = (wg & 511) * 64 + wid * 16;
    int nbase = (wg >> 9) * 128;
    int col = lane & 15, kgrp = lane >> 4;
    f4 acc[8];
#pragma unroll
    for (int i = 0; i < 8; ++i) acc[i] = (f4){0.f, 0.f, 0.f, 0.f};
    const __bf16* ap = xbf + (size_t)(mbase + col) * 512 + kgrp * 8;
    for (int kk = 0; kk < 16; ++kk) {
        bf8 a = *reinterpret_cast<const bf8*>(ap + kk * 32);
        const __bf16* wb = w0hi + (size_t)(nbase + col) * 512 + kk * 32 + kgrp * 8;
        const __bf16* wl = w0lo + (size_t)(nbase + col) * 512 + kk * 32 + kgrp * 8;
#pragma unroll
        for (int ct = 0; ct < 8; ++ct) {
            bf8 bh = *reinterpret_cast<const bf8*>(wb + (size_t)ct * 16 * 512);
            bf8 bl = *reinterpret_cast<const bf8*>(wl + (size_t)ct * 16 * 512);
            acc[ct] = mfma16(a, bh, acc[ct]);
            acc[ct] = mfma16(a, bl, acc[ct]);
        }
    }
#pragma unroll
    for (int ct = 0; ct < 8; ++ct) {
        int c = nbase + ct * 16 + col;
        float bias = b_in0[c];
#pragma unroll
        for (int r = 0; r < 4; ++r) {
            int row = mbase + kgrp * 4 + r;
            ti0[(size_t)row * 512 + c] = acc[ct][r] + bias;
        }
    }
}

// ---------------- persistent recurrence
__global__ __launch_bounds__(192, 1) void k_recur(
    const float* __restrict__ wh0, const float* __restrict__ bh0g,
    const float* __restrict__ win1, const float* __restrict__ bin1g,
    const float* __restrict__ wh1, const float* __restrict__ bh1g,
    const float* __restrict__ ti0,
    float* __restrict__ out,
    unsigned* __restrict__ ws)
{
    // planes: 0:w0r_hi 1:w0r_lo 2:w0m_hi 3:w0m_lo 4:w1r_hi 5:w1r_lo 6:w1m_hi 7:w1m_lo 8:wt_hi
    __shared__ __bf16 sW[9][8192];
    __shared__ float  sTi1[2][256];
    __shared__ float  sMn[2][256];
    __shared__ float  sB[5][16];
    __shared__ int    sAready, sAout, sBdone, sCdone;

    int tid = threadIdx.x, lane = tid & 63, wid = tid >> 6;   // 0=A,1=B,2=C
    int wg = blockIdx.x;
    int rank  = wg & 31;
    int mhalf = wg >> 5;

    unsigned* flagsA = ws + mhalf * 64;
    unsigned* flagsB = ws + 128 + mhalf * 64;
    unsigned* ring0d = ws + 256;
    unsigned* ring1d = ws + 256 + 16384;
    float* fc = (float*)(ws + 33024);

    int h0 = rank * 16;
    int col = lane & 15, kgrp = lane >> 4;
    int rbrow = mhalf * 16;

    // ---- weights to LDS (XOR-swizzled)
    for (int i = tid; i < 8192; i += 192) {
        int cl = i & 15, k = i >> 4;
        int sw = (cl * 512 + k) ^ ((cl & 7) << 3);
        float v0r = wh0[(size_t)k * 1024 + h0 + cl];
        float v0m = wh0[(size_t)k * 1024 + 512 + h0 + cl];
        float v1r = wh1[(size_t)k * 1024 + h0 + cl];
        float v1m = wh1[(size_t)k * 1024 + 512 + h0 + cl];
        float vt  = win1[(size_t)k * 512 + h0 + cl];
        __bf16 a;
        a = (__bf16)v0r; sW[0][sw] = a; sW[1][sw] = (__bf16)(v0r - (float)a);
        a = (__bf16)v0m; sW[2][sw] = a; sW[3][sw] = (__bf16)(v0m - (float)a);
        a = (__bf16)v1r; sW[4][sw] = a; sW[5][sw] = (__bf16)(v1r - (float)a);
        a = (__bf16)v1m; sW[6][sw] = a; sW[7][sw] = (__bf16)(v1m - (float)a);
        sW[8][sw] = (__bf16)vt;
    }
    if (tid < 16) {
        sB[0][tid] = bh0g[h0 + tid];
        sB[1][tid] = bh0g[512 + h0 + tid];
        sB[2][tid] = bh1g[h0 + tid];
        sB[3][tid] = bh1g[512 + h0 + tid];
        sB[4][tid] = bin1g[h0 + tid];
    }
    if (tid == 0) { sAready = -1; sAout = -1; sBdone = -1; sCdone = -1; }
    __syncthreads();

    float cs[4] = {0.f, 0.f, 0.f, 0.f};

    if (wid == 0) {
        // ================= wave A: layer-0 (the binding cycle) + ti1 =================
#pragma unroll 1
        for (int ph = 0; ph <= T_STEPS; ++ph) {
            float t0v[4] = {0.f, 0.f, 0.f, 0.f};
            if (ph < T_STEPS) {
#pragma unroll
                for (int r = 0; r < 4; ++r)
                    t0v[r] = ti0[((size_t)ph * 32 + rbrow + kgrp * 4 + r) * 512 + h0 + col];
            }
            if (ph > 0) {
                const unsigned tgt = (unsigned)ph;
                const unsigned* fp = flagsA + (lane & 31);
                while (true) {
                    unsigned v = __hip_atomic_load(fp, __ATOMIC_RELAXED,
                                                   __HIP_MEMORY_SCOPE_AGENT);
                    if (__ballot(v >= tgt) == ~0ull) break;
                    __builtin_amdgcn_s_sleep(1);
                }
                __builtin_amdgcn_sched_barrier(0);
            }
            // ring0 pull: 16 x dwordx4 sc1 (agent-coherent, same bit as atomic path)
            u32x4 au[16];
            {
                const unsigned* rp = ring0d + ((ph + 1) & 1) * 8192 + (rbrow + col) * 256 + kgrp * 4;
#pragma unroll
                for (int kk = 0; kk < 16; ++kk)
                    asm volatile("global_load_dwordx4 %0, %1, off sc1"
                                 : "=v"(au[kk]) : "v"(rp + kk * 16));
                asm volatile("s_waitcnt vmcnt(0)" ::: "memory");
            }
            f4 accR = {0.f, 0.f, 0.f, 0.f};
            f4 accM = {0.f, 0.f, 0.f, 0.f};
            f4 accT = {0.f, 0.f, 0.f, 0.f};
#pragma unroll
            for (int kk = 0; kk < 16; ++kk) {
                union { u32x4 u; bf8 v; } A;
                A.u = au[kk];
                int e = (col * 512 + kk * 32 + kgrp * 8) ^ ((col & 7) << 3);
                accR = mfma16(A.v, *reinterpret_cast<const bf8*>(&sW[0][e]), accR);
                accR = mfma16(A.v, *reinterpret_cast<const bf8*>(&sW[1][e]), accR);
                accM = mfma16(A.v, *reinterpret_cast<const bf8*>(&sW[2][e]), accM);
                accM = mfma16(A.v, *reinterpret_cast<const bf8*>(&sW[3][e]), accM);
                accT = mfma16(A.v, *reinterpret_cast<const bf8*>(&sW[8][e]), accT);
            }
            // hand ti1 to B (double-buffered slot, back-pressured by sBdone)
            wait_lds_ge(&sBdone, ph - 2);
#pragma unroll
            for (int r = 0; r < 4; ++r)
                sTi1[ph & 1][(kgrp * 4 + r) * 16 + col] = accT[r] + sB[4][col];
            if (lane == 0) set_lds(&sAready, ph);

            if (ph < T_STEPS) {
                float mn[4];
#pragma unroll
                for (int r = 0; r < 4; ++r) {
                    float retain = sigf(accR[r] + sB[0][col]);
                    float merge  = sigf(accM[r] + sB[1][col]);
                    float cv = tanhfast(cs[r] + retain * t0v[r]);
                    cs[r] = cv;
                    mn[r] = (1.f - merge) * t0v[r] + merge * cv;
                }
#pragma unroll
                for (int r = 0; r < 4; ++r) {
                    float hi = __shfl_xor(mn[r], 1, 64);
                    if (!(col & 1)) {
                        int grow = rbrow + kgrp * 4 + r;
                        __hip_atomic_store(&ring0d[(ph & 1) * 8192 + grow * 256 + rank * 8 + (col >> 1)],
                                           pack2(mn[r], hi), __ATOMIC_RELAXED,
                                           __HIP_MEMORY_SCOPE_AGENT);
                    }
                }
                asm volatile("s_waitcnt vmcnt(0)" ::: "memory");
                if (lane == 0)
                    __hip_atomic_store(&flagsA[rank], (unsigned)(ph + 1), __ATOMIC_RELAXED,
                                       __HIP_MEMORY_SCOPE_AGENT);
                // hand mn to C for the out-stores (off the critical path)
                wait_lds_ge(&sCdone, ph - 2);
#pragma unroll
                for (int r = 0; r < 4; ++r)
                    sMn[ph & 1][(kgrp * 4 + r) * 16 + col] = mn[r];
                if (lane == 0) set_lds(&sAout, ph);
            }
        }
#pragma unroll
        for (int r = 0; r < 4; ++r) {
            int b = rbrow + kgrp * 4 + r;
            fc[((size_t)b * 2 + 0) * 512 + h0 + col] = cs[r];
        }
    } else if (wid == 1) {
        // ================= wave B: layer-1 (1-phase slack) =================
#pragma unroll 1
        for (int ph = 1; ph <= T_STEPS; ++ph) {
            if (ph >= 2) {
                const unsigned tgt = (unsigned)(ph - 1);
                const unsigned* fp = flagsB + (lane & 31);
                while (true) {
                    unsigned v = __hip_atomic_load(fp, __ATOMIC_RELAXED,
                                                   __HIP_MEMORY_SCOPE_AGENT);
                    if (__ballot(v >= tgt) == ~0ull) break;
                    __builtin_amdgcn_s_sleep(1);
                }
                __builtin_amdgcn_sched_barrier(0);
            }
            u32x4 au[16];
            {
                const unsigned* rp = ring1d + (ph & 1) * 8192 + (rbrow + col) * 256 + kgrp * 4;
#pragma unroll
                for (int kk = 0; kk < 16; ++kk)
                    asm volatile("global_load_dwordx4 %0, %1, off sc1"
                                 : "=v"(au[kk]) : "v"(rp + kk * 16));
                asm volatile("s_waitcnt vmcnt(0)" ::: "memory");
            }
            f4 accR = {0.f, 0.f, 0.f, 0.f};
            f4 accM = {0.f, 0.f, 0.f, 0.f};
#pragma unroll
            for (int kk = 0; kk < 16; ++kk) {
                union { u32x4 u; bf8 v; } A;
                A.u = au[kk];
                int e = (col * 512 + kk * 32 + kgrp * 8) ^ ((col & 7) << 3);
                accR = mfma16(A.v, *reinterpret_cast<const bf8*>(&sW[4][e]), accR);
                accR = mfma16(A.v, *reinterpret_cast<const bf8*>(&sW[5][e]), accR);
                accM = mfma16(A.v, *reinterpret_cast<const bf8*>(&sW[6][e]), accM);
                accM = mfma16(A.v, *reinterpret_cast<const bf8*>(&sW[7][e]), accM);
            }
            wait_lds_ge(&sAready, ph);
            float mn[4];
#pragma unroll
            for (int r = 0; r < 4; ++r) {
                float t1v = sTi1[ph & 1][(kgrp * 4 + r) * 16 + col];
                float retain = sigf(accR[r] + sB[2][col]);
                float merge  = sigf(accM[r] + sB[3][col]);
                float cv = tanhfast(cs[r] + retain * t1v);
                cs[r] = cv;
                mn[r] = (1.f - merge) * t1v + merge * cv;
            }
            if (lane == 0) set_lds(&sBdone, ph);
#pragma unroll
            for (int r = 0; r < 4; ++r) {
                float hi = __shfl_xor(mn[r], 1, 64);
                if (!(col & 1)) {
                    int grow = rbrow + kgrp * 4 + r;
                    __hip_atomic_store(&ring1d[((ph + 1) & 1) * 8192 + grow * 256 + rank * 8 + (col >> 1)],
                                       pack2(mn[r], hi), __ATOMIC_RELAXED,
                                       __HIP_MEMORY_SCOPE_AGENT);
                }
            }
            asm volatile("s_waitcnt vmcnt(0)" ::: "memory");
            if (lane == 0)
                __hip_atomic_store(&flagsB[rank], (unsigned)ph, __ATOMIC_RELAXED,
                                   __HIP_MEMORY_SCOPE_AGENT);
#pragma unroll
            for (int r = 0; r < 4; ++r) {
                int b = rbrow + kgrp * 4 + r;
                size_t ob = ((size_t)b * 1024 + (ph - 1)) * 1024 + 512 + h0 + col;
                __builtin_nontemporal_store(mn[r], out + ob);
                __builtin_nontemporal_store(mn[r], out + (size_t)33554432 + ob);
            }
        }
#pragma unroll
        for (int r = 0; r < 4; ++r) {
            int b = rbrow + kgrp * 4 + r;
            fc[((size_t)b * 2 + 1) * 512 + h0 + col] = cs[r];
        }
    } else {
        // ================= wave C: layer-0 output stores =================
#pragma unroll 1
        for (int ph = 0; ph < T_STEPS; ++ph) {
            wait_lds_ge(&sAout, ph);
            float mn[4];
#pragma unroll
            for (int r = 0; r < 4; ++r)
                mn[r] = sMn[ph & 1][(kgrp * 4 + r) * 16 + col];
            if (lane == 0) set_lds(&sCdone, ph);
#pragma unroll
            for (int r = 0; r < 4; ++r) {
                int b = rbrow + kgrp * 4 + r;
                size_t ob = ((size_t)b * 1024 + ph) * 1024 + h0 + col;
                __builtin_nontemporal_store(mn[r], out + ob);
                __builtin_nontemporal_store(mn[r], out + (size_t)33554432 + ob);
            }
        }
    }
}

__global__ __launch_bounds__(256) void k_final(const float* __restrict__ fc,
                                               float* __restrict__ seg2)
{
    size_t id = (size_t)blockIdx.x * 256 + threadIdx.x;
    size_t gs = (size_t)gridDim.x * 256;
    for (size_t i = id; i < (size_t)8388608; i += gs) {
        size_t flat = i * 4;
        int h = (int)(flat & 511);
        int l = (int)((flat >> 9) & 1);
        int b = (int)(flat >> 20);
        f4 v = *reinterpret_cast<const f4*>(&fc[((size_t)b * 2 + l) * 512 + h]);
        *reinterpret_cast<f4*>(&seg2[flat]) = v;
    }
}

extern "C" void kernel_launch(void* const* d_in, const int* in_sizes, int n_in,
                              void* d_out, int out_size, void* d_ws, size_t ws_size,
                              hipStream_t stream)
{
    const float* x     = (const float*)d_in[0];
    const float* w_in0 = (const float*)d_in[1];
    const float* b_in0 = (const float*)d_in[2];
    const float* wh0   = (const float*)d_in[3];
    const float* bh0   = (const float*)d_in[4];
    const float* win1  = (const float*)d_in[5];
    const float* bin1  = (const float*)d_in[6];
    const float* wh1   = (const float*)d_in[7];
    const float* bh1   = (const float*)d_in[8];
    float* out = (float*)d_out;

    float*  seg2 = out + (size_t)2 * 33554432;
    float*  ti0  = seg2;
    __bf16* xbf  = (__bf16*)(ti0 + 16777216);
    __bf16* w0hi = xbf + 16777216;
    __bf16* w0lo = w0hi + 262144;

    k_init<<<1024, 256, 0, stream>>>(x, w_in0, xbf, w0hi, w0lo, (unsigned*)d_ws);
    k_pregemm<<<2048, 256, 0, stream>>>(xbf, w0hi, w0lo, b_in0, ti0);
    k_recur<<<64, 192, 0, stream>>>(wh0, bh0, win1, bin1, wh1, bh1, ti0, out,
                                    (unsigned*)d_ws);
    k_final<<<1024, 256, 0, stream>>>((const float*)((unsigned*)d_ws + 33024), seg2);
}